// Round 14
// baseline (947.204 us; speedup 1.0000x reference)
//
#include <hip/hip_runtime.h>

#define PROP_ALPHA 0.1f
#define PROP_KSTEPS 10
#define NBUCK 1024
#define BSHIFT 6
#define BCAP 1536
#define OVCAP 4096

typedef _Float16 half_t;

// ---------------- CSR build (binned two-pass scatter) ----------------

// pass 1: degree histogram + bin edges by dst>>BSHIFT (clustered appends)
__global__ void binscatter1_kernel(const int* __restrict__ src, const int* __restrict__ dst,
                                   int* __restrict__ degI, int* __restrict__ bctr,
                                   long long* __restrict__ bbuf,
                                   long long* __restrict__ ovbuf, int* __restrict__ ovct,
                                   int E) {
    int e = blockIdx.x * blockDim.x + threadIdx.x;
    if (e < E) {
        int d = dst[e], s = src[e];
        atomicAdd(&degI[d], 1);
        int b = d >> BSHIFT;
        int bp = atomicAdd(&bctr[b], 1);
        long long packed = ((long long)d << 32) | (unsigned int)s;
        if (bp < BCAP) {
            __builtin_nontemporal_store(packed, &bbuf[(size_t)b * BCAP + bp]);
        } else {
            int op = atomicAdd(ovct, 1);
            if (op < OVCAP) ovbuf[op] = packed;
        }
    }
}

__global__ void dinv_kernel(const int* __restrict__ degI, float* __restrict__ dinv, int N) {
    int i = blockIdx.x * blockDim.x + threadIdx.x;
    if (i < N) {
        float d = (float)(degI[i] + 1);   // + self loop
        dinv[i] = rsqrtf(d);
    }
}

__global__ __launch_bounds__(256) void scan1_kernel(const int* __restrict__ degI,
                                                    int* __restrict__ rowptr,
                                                    int* __restrict__ blockSums, int N) {
    __shared__ int s[256];
    int t = threadIdx.x;
    int idx = blockIdx.x * 256 + t;
    s[t] = (idx < N) ? degI[idx] : 0;
    __syncthreads();
    for (int off = 1; off < 256; off <<= 1) {
        int x = (t >= off) ? s[t - off] : 0;
        __syncthreads();
        s[t] += x;
        __syncthreads();
    }
    if (idx < N) rowptr[idx + 1] = s[t];
    if (t == 255) blockSums[blockIdx.x] = s[255];
    if (blockIdx.x == 0 && t == 0) rowptr[0] = 0;
}

__global__ __launch_bounds__(256) void scan2_kernel(int* __restrict__ blockSums, int nB) {
    __shared__ int s[256];
    int t = threadIdx.x;
    s[t] = (t < nB) ? blockSums[t] : 0;
    __syncthreads();
    for (int off = 1; off < 256; off <<= 1) {
        int x = (t >= off) ? s[t - off] : 0;
        __syncthreads();
        s[t] += x;
        __syncthreads();
    }
    if (t < nB) blockSums[t] = (t == 0) ? 0 : s[t - 1];
}

__global__ void scan3_kernel(int* __restrict__ rowptr, const int* __restrict__ blockSums,
                             int N) {
    int idx = blockIdx.x * 256 + threadIdx.x;
    if (idx < N) rowptr[idx + 1] += blockSums[blockIdx.x];
}

// pass 2: one block per bucket; edata writes land in a contiguous ~12 KB window
__global__ __launch_bounds__(256) void binscatter2_kernel(const long long* __restrict__ bbuf,
                                                          const int* __restrict__ bctr,
                                                          const int* __restrict__ rowptr,
                                                          int* __restrict__ rowctr,
                                                          const float* __restrict__ dinv,
                                                          long long* __restrict__ edata) {
    int b = blockIdx.x;
    int cnt = min(bctr[b], BCAP);
    for (int j = threadIdx.x; j < cnt; j += 256) {
        long long packed = bbuf[(size_t)b * BCAP + j];
        int s = (int)packed;
        int d = (int)(packed >> 32);
        int p = rowptr[d] + atomicAdd(&rowctr[d], 1);
        long long ed = ((long long)__float_as_int(dinv[s] * dinv[d]) << 32)
                     | (unsigned int)s;
        __builtin_nontemporal_store(ed, &edata[p]);
    }
}

__global__ __launch_bounds__(256) void binoverflow_kernel(const long long* __restrict__ ovbuf,
                                                          const int* __restrict__ ovct,
                                                          const int* __restrict__ rowptr,
                                                          int* __restrict__ rowctr,
                                                          const float* __restrict__ dinv,
                                                          long long* __restrict__ edata) {
    int n = min(*ovct, OVCAP);
    for (int j = threadIdx.x; j < n; j += 256) {
        long long packed = ovbuf[j];
        int s = (int)packed;
        int d = (int)(packed >> 32);
        int p = rowptr[d] + atomicAdd(&rowctr[d], 1);
        long long ed = ((long long)__float_as_int(dinv[s] * dinv[d]) << 32)
                     | (unsigned int)s;
        edata[p] = ed;
    }
}

// ---------------- fused MLP: h2 = relu(zx@W3 + v*b3^T)@W4 + b4 ----------------

__global__ __launch_bounds__(256) void fusedmlp_kernel(const float* __restrict__ zx,
                                                       const float* __restrict__ v,
                                                       const float* __restrict__ W3,
                                                       const float* __restrict__ b3,
                                                       const float* __restrict__ W4,
                                                       const float* __restrict__ b4,
                                                       float* __restrict__ h2, int N) {
    __shared__ float Ws[64 * 128];    // 32 KB: W3 [k][128] then W4 [k][64]
    __shared__ float zsT[64 * 36];    // [k][row], padded stride 36
    __shared__ float ts[32 * 132];    // [row][k], padded stride 132
    __shared__ float vs[32];
    int t = threadIdx.x;
    int r0 = blockIdx.x * 32;
    int rows = min(32, N - r0);

    for (int idx = t; idx < 64 * 128; idx += 256) Ws[idx] = W3[idx];
    for (int idx = t; idx < 32 * 64; idx += 256) {
        int r = idx >> 6, c = idx & 63;
        zsT[c * 36 + r] = (r < rows) ? zx[(size_t)(r0 + r) * 64 + c] : 0.0f;
    }
    if (t < 32) vs[t] = (t < rows) ? v[r0 + t] : 0.0f;
    __syncthreads();

    // ---- layer 1 ----
    {
        int cq = t & 31, rq = t >> 5;
        int cb = cq * 4, rb = rq * 4;
        float4 b3v = *reinterpret_cast<const float4*>(&b3[cb]);
        float a[4][4];
        #pragma unroll
        for (int ri = 0; ri < 4; ++ri) {
            float vv = vs[rb + ri];
            a[ri][0] = vv * b3v.x; a[ri][1] = vv * b3v.y;
            a[ri][2] = vv * b3v.z; a[ri][3] = vv * b3v.w;
        }
        #pragma unroll 4
        for (int k = 0; k < 64; ++k) {
            float4 zq = *reinterpret_cast<const float4*>(&zsT[k * 36 + rb]);
            float4 wq = *reinterpret_cast<const float4*>(&Ws[k * 128 + cb]);
            a[0][0] += zq.x * wq.x; a[0][1] += zq.x * wq.y;
            a[0][2] += zq.x * wq.z; a[0][3] += zq.x * wq.w;
            a[1][0] += zq.y * wq.x; a[1][1] += zq.y * wq.y;
            a[1][2] += zq.y * wq.z; a[1][3] += zq.y * wq.w;
            a[2][0] += zq.z * wq.x; a[2][1] += zq.z * wq.y;
            a[2][2] += zq.z * wq.z; a[2][3] += zq.z * wq.w;
            a[3][0] += zq.w * wq.x; a[3][1] += zq.w * wq.y;
            a[3][2] += zq.w * wq.z; a[3][3] += zq.w * wq.w;
        }
        #pragma unroll
        for (int ri = 0; ri < 4; ++ri) {
            float4 o;
            o.x = fmaxf(a[ri][0], 0.0f); o.y = fmaxf(a[ri][1], 0.0f);
            o.z = fmaxf(a[ri][2], 0.0f); o.w = fmaxf(a[ri][3], 0.0f);
            *reinterpret_cast<float4*>(&ts[(rb + ri) * 132 + cb]) = o;
        }
    }
    __syncthreads();
    for (int idx = t; idx < 128 * 64; idx += 256) Ws[idx] = W4[idx];
    __syncthreads();

    // ---- layer 2 ----
    {
        int cg = t & 15, rg = t >> 4;
        int cb = cg * 4, rb = rg * 2;
        float4 b4v = *reinterpret_cast<const float4*>(&b4[cb]);
        float a[2][4];
        #pragma unroll
        for (int ri = 0; ri < 2; ++ri) {
            a[ri][0] = b4v.x; a[ri][1] = b4v.y; a[ri][2] = b4v.z; a[ri][3] = b4v.w;
        }
        #pragma unroll 4
        for (int k = 0; k < 128; ++k) {
            float t0 = ts[rb * 132 + k];
            float t1 = ts[(rb + 1) * 132 + k];
            float4 wq = *reinterpret_cast<const float4*>(&Ws[k * 64 + cb]);
            a[0][0] += t0 * wq.x; a[0][1] += t0 * wq.y;
            a[0][2] += t0 * wq.z; a[0][3] += t0 * wq.w;
            a[1][0] += t1 * wq.x; a[1][1] += t1 * wq.y;
            a[1][2] += t1 * wq.z; a[1][3] += t1 * wq.w;
        }
        #pragma unroll
        for (int ri = 0; ri < 2; ++ri) {
            int r = rb + ri;
            if (r < rows) {
                float4 o = {a[ri][0], a[ri][1], a[ri][2], a[ri][3]};
                *reinterpret_cast<float4*>(&h2[(size_t)(r0 + r) * 64 + cb]) = o;
            }
        }
    }
}

// ---------------- propagation ----------------
// Wave = 2 contiguous nodes interleaved, lane = channel, 1 edge per gather
// instr. Intermediate z stored fp16 (128 B rows); compute fp32; TI/TO select
// fp32 bridges at phase boundaries.

template <typename TI, bool WITHV>
__device__ inline void drain_node(const TI* __restrict__ zin,
                                  const long long* __restrict__ edata,
                                  int& e, int end, int lane,
                                  float& a0, float& a1, float& a2, float& a3,
                                  const float* __restrict__ vin, float& vacc,
                                  int firstOnes) {
    for (; e + 8 <= end; e += 8) {
        long long p0 = edata[e],     p1 = edata[e + 1], p2 = edata[e + 2], p3 = edata[e + 3];
        long long p4 = edata[e + 4], p5 = edata[e + 5], p6 = edata[e + 6], p7 = edata[e + 7];
        int s0 = (int)p0, s1 = (int)p1, s2 = (int)p2, s3 = (int)p3;
        int s4 = (int)p4, s5 = (int)p5, s6 = (int)p6, s7 = (int)p7;
        float n0 = __int_as_float((int)(p0 >> 32)), n1 = __int_as_float((int)(p1 >> 32));
        float n2 = __int_as_float((int)(p2 >> 32)), n3 = __int_as_float((int)(p3 >> 32));
        float n4 = __int_as_float((int)(p4 >> 32)), n5 = __int_as_float((int)(p5 >> 32));
        float n6 = __int_as_float((int)(p6 >> 32)), n7 = __int_as_float((int)(p7 >> 32));
        float v0 = (float)zin[(size_t)s0 * 64 + lane];
        float v1 = (float)zin[(size_t)s1 * 64 + lane];
        float v2 = (float)zin[(size_t)s2 * 64 + lane];
        float v3 = (float)zin[(size_t)s3 * 64 + lane];
        float v4 = (float)zin[(size_t)s4 * 64 + lane];
        float v5 = (float)zin[(size_t)s5 * 64 + lane];
        float v6 = (float)zin[(size_t)s6 * 64 + lane];
        float v7 = (float)zin[(size_t)s7 * 64 + lane];
        if (WITHV) {
            if (firstOnes) vacc += (n0 + n1 + n2 + n3) + (n4 + n5 + n6 + n7);
            else vacc += n0 * vin[s0] + n1 * vin[s1] + n2 * vin[s2] + n3 * vin[s3]
                       + n4 * vin[s4] + n5 * vin[s5] + n6 * vin[s6] + n7 * vin[s7];
        }
        a0 += n0 * v0; a1 += n1 * v1; a2 += n2 * v2; a3 += n3 * v3;
        a0 += n4 * v4; a1 += n5 * v5; a2 += n6 * v6; a3 += n7 * v7;
    }
    for (; e + 2 <= end; e += 2) {
        long long p0 = edata[e], p1 = edata[e + 1];
        int s0 = (int)p0, s1 = (int)p1;
        float n0 = __int_as_float((int)(p0 >> 32)), n1 = __int_as_float((int)(p1 >> 32));
        float v0 = (float)zin[(size_t)s0 * 64 + lane];
        float v1 = (float)zin[(size_t)s1 * 64 + lane];
        if (WITHV) {
            vacc += firstOnes ? (n0 + n1) : (n0 * vin[s0] + n1 * vin[s1]);
        }
        a0 += n0 * v0; a1 += n1 * v1;
    }
    if (e < end) {
        long long p0 = edata[e];
        int s0 = (int)p0;
        float n0 = __int_as_float((int)(p0 >> 32));
        a0 += n0 * (float)zin[(size_t)s0 * 64 + lane];
        if (WITHV) vacc += firstOnes ? n0 : n0 * vin[s0];
        ++e;
    }
}

template <typename TI, typename TO, bool WITHV>
__global__ __launch_bounds__(256) void prop64_kernel(const TI* __restrict__ zin,
                                                     const float* __restrict__ h,
                                                     const int* __restrict__ rowptr,
                                                     const long long* __restrict__ edata,
                                                     const float* __restrict__ dinv,
                                                     TO* __restrict__ zout,
                                                     const float* __restrict__ vin,
                                                     float* __restrict__ vout,
                                                     int N, int firstOnes) {
    int wave = threadIdx.x >> 6;
    int lane = threadIdx.x & 63;
    int pair = blockIdx.x * 4 + wave;
    int iA = pair * 2;
    if (iA >= N) return;
    iA = __builtin_amdgcn_readfirstlane(iA);
    int iB = iA + 1;
    bool hasB = (iB < N);
    int begA = rowptr[iA], endA = rowptr[iA + 1];
    int begB = endA, endB = hasB ? rowptr[iB + 1] : endA;
    float diA = dinv[iA];
    float diB = hasB ? dinv[iB] : 0.0f;
    size_t liA = (size_t)iA * 64 + lane;
    size_t liB = (size_t)iB * 64 + lane;
    float a0 = diA * diA * (float)zin[liA], a1 = 0.0f, a2 = 0.0f, a3 = 0.0f;
    float b0 = hasB ? diB * diB * (float)zin[liB] : 0.0f, b1 = 0.0f, b2 = 0.0f, b3 = 0.0f;
    float vaccA = 0.0f, vaccB = 0.0f;
    int eA = begA, eB = begB;

    while (eA + 8 <= endA && eB + 8 <= endB) {
        long long pA0 = edata[eA],     pA1 = edata[eA + 1];
        long long pA2 = edata[eA + 2], pA3 = edata[eA + 3];
        long long pA4 = edata[eA + 4], pA5 = edata[eA + 5];
        long long pA6 = edata[eA + 6], pA7 = edata[eA + 7];
        long long pB0 = edata[eB],     pB1 = edata[eB + 1];
        long long pB2 = edata[eB + 2], pB3 = edata[eB + 3];
        long long pB4 = edata[eB + 4], pB5 = edata[eB + 5];
        long long pB6 = edata[eB + 6], pB7 = edata[eB + 7];
        int sA0 = (int)pA0, sA1 = (int)pA1, sA2 = (int)pA2, sA3 = (int)pA3;
        int sA4 = (int)pA4, sA5 = (int)pA5, sA6 = (int)pA6, sA7 = (int)pA7;
        int sB0 = (int)pB0, sB1 = (int)pB1, sB2 = (int)pB2, sB3 = (int)pB3;
        int sB4 = (int)pB4, sB5 = (int)pB5, sB6 = (int)pB6, sB7 = (int)pB7;
        float nA0 = __int_as_float((int)(pA0 >> 32)), nA1 = __int_as_float((int)(pA1 >> 32));
        float nA2 = __int_as_float((int)(pA2 >> 32)), nA3 = __int_as_float((int)(pA3 >> 32));
        float nA4 = __int_as_float((int)(pA4 >> 32)), nA5 = __int_as_float((int)(pA5 >> 32));
        float nA6 = __int_as_float((int)(pA6 >> 32)), nA7 = __int_as_float((int)(pA7 >> 32));
        float nB0 = __int_as_float((int)(pB0 >> 32)), nB1 = __int_as_float((int)(pB1 >> 32));
        float nB2 = __int_as_float((int)(pB2 >> 32)), nB3 = __int_as_float((int)(pB3 >> 32));
        float nB4 = __int_as_float((int)(pB4 >> 32)), nB5 = __int_as_float((int)(pB5 >> 32));
        float nB6 = __int_as_float((int)(pB6 >> 32)), nB7 = __int_as_float((int)(pB7 >> 32));
        float vA0 = (float)zin[(size_t)sA0 * 64 + lane];
        float vA1 = (float)zin[(size_t)sA1 * 64 + lane];
        float vA2 = (float)zin[(size_t)sA2 * 64 + lane];
        float vA3 = (float)zin[(size_t)sA3 * 64 + lane];
        float vA4 = (float)zin[(size_t)sA4 * 64 + lane];
        float vA5 = (float)zin[(size_t)sA5 * 64 + lane];
        float vA6 = (float)zin[(size_t)sA6 * 64 + lane];
        float vA7 = (float)zin[(size_t)sA7 * 64 + lane];
        float vB0 = (float)zin[(size_t)sB0 * 64 + lane];
        float vB1 = (float)zin[(size_t)sB1 * 64 + lane];
        float vB2 = (float)zin[(size_t)sB2 * 64 + lane];
        float vB3 = (float)zin[(size_t)sB3 * 64 + lane];
        float vB4 = (float)zin[(size_t)sB4 * 64 + lane];
        float vB5 = (float)zin[(size_t)sB5 * 64 + lane];
        float vB6 = (float)zin[(size_t)sB6 * 64 + lane];
        float vB7 = (float)zin[(size_t)sB7 * 64 + lane];
        if (WITHV) {
            if (firstOnes) {
                vaccA += (nA0 + nA1 + nA2 + nA3) + (nA4 + nA5 + nA6 + nA7);
                vaccB += (nB0 + nB1 + nB2 + nB3) + (nB4 + nB5 + nB6 + nB7);
            } else {
                vaccA += nA0 * vin[sA0] + nA1 * vin[sA1] + nA2 * vin[sA2]
                       + nA3 * vin[sA3] + nA4 * vin[sA4] + nA5 * vin[sA5]
                       + nA6 * vin[sA6] + nA7 * vin[sA7];
                vaccB += nB0 * vin[sB0] + nB1 * vin[sB1] + nB2 * vin[sB2]
                       + nB3 * vin[sB3] + nB4 * vin[sB4] + nB5 * vin[sB5]
                       + nB6 * vin[sB6] + nB7 * vin[sB7];
            }
        }
        a0 += nA0 * vA0; a1 += nA1 * vA1; a2 += nA2 * vA2; a3 += nA3 * vA3;
        a0 += nA4 * vA4; a1 += nA5 * vA5; a2 += nA6 * vA6; a3 += nA7 * vA7;
        b0 += nB0 * vB0; b1 += nB1 * vB1; b2 += nB2 * vB2; b3 += nB3 * vB3;
        b0 += nB4 * vB4; b1 += nB5 * vB5; b2 += nB6 * vB6; b3 += nB7 * vB7;
        eA += 8; eB += 8;
    }
    drain_node<TI, WITHV>(zin, edata, eA, endA, lane, a0, a1, a2, a3, vin, vaccA, firstOnes);
    if (hasB)
        drain_node<TI, WITHV>(zin, edata, eB, endB, lane, b0, b1, b2, b3, vin, vaccB, firstOnes);

    float accA = (a0 + a1) + (a2 + a3);
    zout[liA] = (TO)((1.0f - PROP_ALPHA) * accA + PROP_ALPHA * h[liA]);
    if (hasB) {
        float accB = (b0 + b1) + (b2 + b3);
        zout[liB] = (TO)((1.0f - PROP_ALPHA) * accB + PROP_ALPHA * h[liB]);
    }
    if (WITHV) {
        if (lane == 0) {
            float selfA = firstOnes ? 1.0f : vin[iA];
            vout[iA] = (1.0f - PROP_ALPHA) * (vaccA + diA * diA * selfA) + PROP_ALPHA;
            if (hasB) {
                float selfB = firstOnes ? 1.0f : vin[iB];
                vout[iB] = (1.0f - PROP_ALPHA) * (vaccB + diB * diB * selfB) + PROP_ALPHA;
            }
        }
    }
}

// ---------------- launch ----------------

extern "C" void kernel_launch(void* const* d_in, const int* in_sizes, int n_in,
                              void* d_out, int out_size, void* d_ws, size_t ws_size,
                              hipStream_t stream) {
    const float* x  = (const float*)d_in[0];
    const int*   ei = (const int*)d_in[1];
    const float* W3 = (const float*)d_in[2];
    const float* b3 = (const float*)d_in[3];
    const float* W4 = (const float*)d_in[4];
    const float* b4 = (const float*)d_in[5];
    float* out = (float*)d_out;

    int N = in_sizes[0] / 64;   // IN_CH = 64
    int E = in_sizes[1] / 2;
    const int* srcA = ei;
    const int* dstA = ei + E;

    char* ws = (char*)d_ws;
    size_t off = 0;
    auto alloc = [&](size_t bytes) -> void* {
        void* p = ws + off;
        off = (off + bytes + 255) & ~(size_t)255;
        return p;
    };

    int nScanB = (N + 255) / 256;

    int*       degI   = (int*)alloc((size_t)N * 4);
    int*       rowptr = (int*)alloc(((size_t)N + 1) * 4);
    int*       rowctr = (int*)alloc((size_t)N * 4);
    int*       bsums  = (int*)alloc((size_t)nScanB * 4);
    int*       bctr   = (int*)alloc((size_t)NBUCK * 4);
    int*       ovct   = (int*)alloc(256);
    long long* bbuf   = (long long*)alloc((size_t)NBUCK * BCAP * 8);
    long long* ovbuf  = (long long*)alloc((size_t)OVCAP * 8);
    float*     dinv   = (float*)alloc((size_t)N * 4);
    long long* edata  = (long long*)alloc((size_t)E * 8);
    float*     vA     = (float*)alloc((size_t)N * 4);
    float*     vB     = (float*)alloc((size_t)N * 4);
    half_t*    z16A   = (half_t*)alloc((size_t)N * 64 * 2);
    half_t*    z16B   = (half_t*)alloc((size_t)N * 64 * 2);
    float*     zxf    = (float*)alloc((size_t)N * 64 * 4);
    float*     hbuf   = (float*)alloc((size_t)N * 64 * 4);

    hipMemsetAsync(degI, 0, (size_t)N * 4, stream);
    hipMemsetAsync(rowctr, 0, (size_t)N * 4, stream);
    hipMemsetAsync(bctr, 0, (size_t)NBUCK * 4, stream);
    hipMemsetAsync(ovct, 0, 256, stream);

    // --- CSR build: binned two-pass scatter ---
    binscatter1_kernel<<<(E + 255) / 256, 256, 0, stream>>>(srcA, dstA, degI, bctr,
                                                            bbuf, ovbuf, ovct, E);
    dinv_kernel<<<(N + 255) / 256, 256, 0, stream>>>(degI, dinv, N);
    scan1_kernel<<<nScanB, 256, 0, stream>>>(degI, rowptr, bsums, N);
    scan2_kernel<<<1, 256, 0, stream>>>(bsums, nScanB);
    scan3_kernel<<<nScanB, 256, 0, stream>>>(rowptr, bsums, N);
    binscatter2_kernel<<<NBUCK, 256, 0, stream>>>(bbuf, bctr, rowptr, rowctr, dinv, edata);
    binoverflow_kernel<<<1, 256, 0, stream>>>(ovbuf, ovct, rowptr, rowctr, dinv, edata);

    int nPairs = (N + 1) / 2;
    int propBlocks = (nPairs + 3) / 4;

    // --- prop1: zx = M*x, z fp16 between steps, fused v = M*ones ---
    for (int s = 0; s < PROP_KSTEPS; ++s) {
        const float* vi = (s & 1) ? vA : vB;   // s0: unused (firstOnes)
        float*       vo = (s & 1) ? vB : vA;
        if (s == 0) vi = vB;
        if (s == 0) {
            prop64_kernel<float, half_t, true><<<propBlocks, 256, 0, stream>>>(
                x, x, rowptr, edata, dinv, z16A, vi, vo, N, 1);
        } else if (s == PROP_KSTEPS - 1) {
            prop64_kernel<half_t, float, true><<<propBlocks, 256, 0, stream>>>(
                z16A, x, rowptr, edata, dinv, zxf, vi, vo, N, 0);
        } else {
            const half_t* in = (s & 1) ? z16A : z16B;
            half_t*       o  = (s & 1) ? z16B : z16A;
            prop64_kernel<half_t, half_t, true><<<propBlocks, 256, 0, stream>>>(
                in, x, rowptr, edata, dinv, o, vi, vo, N, 0);
        }
    }
    // zx in zxf, v in vB

    // --- h2 = relu(zx@W3 + v*b3^T)@W4 + b4 ---
    fusedmlp_kernel<<<(N + 31) / 32, 256, 0, stream>>>(zxf, vB, W3, b3, W4, b4, hbuf, N);

    // --- prop2: out = M*h2 ---
    for (int s = 0; s < PROP_KSTEPS; ++s) {
        if (s == 0) {
            prop64_kernel<float, half_t, false><<<propBlocks, 256, 0, stream>>>(
                hbuf, hbuf, rowptr, edata, dinv, z16A, nullptr, nullptr, N, 0);
        } else if (s == PROP_KSTEPS - 1) {
            prop64_kernel<half_t, float, false><<<propBlocks, 256, 0, stream>>>(
                z16A, hbuf, rowptr, edata, dinv, out, nullptr, nullptr, N, 0);
        } else {
            const half_t* in = (s & 1) ? z16A : z16B;
            half_t*       o  = (s & 1) ? z16B : z16A;
            prop64_kernel<half_t, half_t, false><<<propBlocks, 256, 0, stream>>>(
                in, hbuf, rowptr, edata, dinv, o, nullptr, nullptr, N, 0);
        }
    }
}

// Round 16
// 715.879 us; speedup vs baseline: 1.3231x; 1.3231x over previous
//
#include <hip/hip_runtime.h>

#define PROP_ALPHA 0.1f
#define PROP_KSTEPS 10

typedef _Float16 half_t;
typedef __attribute__((ext_vector_type(4))) _Float16 half4v;

__device__ inline unsigned int f2h15(float w) {
    half_t h = (half_t)w;
    return (unsigned int)__builtin_bit_cast(unsigned short, h) & 0x7FFFu;
}
__device__ inline float h15_2f(unsigned int bits) {
    half_t h = __builtin_bit_cast(half_t, (unsigned short)(bits & 0x7FFFu));
    return (float)h;
}

// ---------------- CSR build ----------------

__global__ void hist_kernel(const int* __restrict__ dst, int* __restrict__ degI, int E) {
    int e = blockIdx.x * blockDim.x + threadIdx.x;
    if (e < E) atomicAdd(&degI[dst[e]], 1);
}

__global__ void dinv_kernel(const int* __restrict__ degI, float* __restrict__ dinv, int N) {
    int i = blockIdx.x * blockDim.x + threadIdx.x;
    if (i < N) {
        float d = (float)(degI[i] + 1);   // + self loop
        dinv[i] = rsqrtf(d);
    }
}

__global__ __launch_bounds__(256) void scan1_kernel(const int* __restrict__ degI,
                                                    int* __restrict__ rowptr,
                                                    int* __restrict__ blockSums, int N) {
    __shared__ int s[256];
    int t = threadIdx.x;
    int idx = blockIdx.x * 256 + t;
    s[t] = (idx < N) ? degI[idx] : 0;
    __syncthreads();
    for (int off = 1; off < 256; off <<= 1) {
        int x = (t >= off) ? s[t - off] : 0;
        __syncthreads();
        s[t] += x;
        __syncthreads();
    }
    if (idx < N) rowptr[idx + 1] = s[t];
    if (t == 255) blockSums[blockIdx.x] = s[255];
    if (blockIdx.x == 0 && t == 0) rowptr[0] = 0;
}

__global__ __launch_bounds__(256) void scan2_kernel(int* __restrict__ blockSums, int nB) {
    __shared__ int s[256];
    int t = threadIdx.x;
    s[t] = (t < nB) ? blockSums[t] : 0;
    __syncthreads();
    for (int off = 1; off < 256; off <<= 1) {
        int x = (t >= off) ? s[t - off] : 0;
        __syncthreads();
        s[t] += x;
        __syncthreads();
    }
    if (t < nB) blockSums[t] = (t == 0) ? 0 : s[t - 1];
}

__global__ void scan3_kernel(int* __restrict__ rowptr, const int* __restrict__ blockSums,
                             int N) {
    int idx = blockIdx.x * 256 + threadIdx.x;
    if (idx < N) rowptr[idx + 1] += blockSums[blockIdx.x];
}

// edata[p] = src<<15 | fp16bits(norm) sans sign — one 4 B store per edge
__global__ void scatter_kernel(const int* __restrict__ src, const int* __restrict__ dst,
                               const int* __restrict__ rowptr, int* __restrict__ rowctr,
                               const float* __restrict__ dinv,
                               int* __restrict__ edata, int E) {
    int e = blockIdx.x * blockDim.x + threadIdx.x;
    if (e < E) {
        int d = dst[e], s = src[e];
        int p = rowptr[d] + atomicAdd(&rowctr[d], 1);
        unsigned int packed = ((unsigned int)s << 15) | f2h15(dinv[s] * dinv[d]);
        __builtin_nontemporal_store((int)packed, &edata[p]);
    }
}

// ---------------- fused MLP: h2 = relu(zx@W3 + v*b3^T)@W4 + b4 ----------------
// zx fp16 in; zsT/ts staged fp16 (LDS ~45 KB -> 3 blocks/CU); compute fp32.
// ts is ROW-MAJOR [32 rows][132 k-stride]; layer-2 reads are scalar broadcast.

__global__ __launch_bounds__(256) void fusedmlp_kernel(const half_t* __restrict__ zx,
                                                       const float* __restrict__ v,
                                                       const float* __restrict__ W3,
                                                       const float* __restrict__ b3,
                                                       const float* __restrict__ W4,
                                                       const float* __restrict__ b4,
                                                       float* __restrict__ h2, int N) {
    __shared__ float Ws[64 * 128];     // 32 KB: W3 [k][128] then W4 [k][64]
    __shared__ half_t zsT[64 * 36];    // [k][row] fp16, padded stride 36
    __shared__ half_t ts[32 * 132];    // [row][k] fp16, padded stride 132
    __shared__ float vs[32];
    int t = threadIdx.x;
    int r0 = blockIdx.x * 32;
    int rows = min(32, N - r0);

    for (int idx = t; idx < 64 * 128; idx += 256) Ws[idx] = W3[idx];
    for (int idx = t; idx < 32 * 64; idx += 256) {
        int r = idx >> 6, c = idx & 63;
        zsT[c * 36 + r] = (r < rows) ? zx[(size_t)(r0 + r) * 64 + c] : (half_t)0.0f;
    }
    if (t < 32) vs[t] = (t < rows) ? v[r0 + t] : 0.0f;
    __syncthreads();

    // ---- layer 1: ts = relu(z @ W3 + v*b3^T) ----
    {
        int cq = t & 31, rq = t >> 5;
        int cb = cq * 4, rb = rq * 4;
        float4 b3v = *reinterpret_cast<const float4*>(&b3[cb]);
        float a[4][4];
        #pragma unroll
        for (int ri = 0; ri < 4; ++ri) {
            float vv = vs[rb + ri];
            a[ri][0] = vv * b3v.x; a[ri][1] = vv * b3v.y;
            a[ri][2] = vv * b3v.z; a[ri][3] = vv * b3v.w;
        }
        #pragma unroll 4
        for (int k = 0; k < 64; ++k) {
            half4v zh = *reinterpret_cast<const half4v*>(&zsT[k * 36 + rb]);
            float z0 = (float)zh.x, z1 = (float)zh.y, z2 = (float)zh.z, z3 = (float)zh.w;
            float4 wq = *reinterpret_cast<const float4*>(&Ws[k * 128 + cb]);
            a[0][0] += z0 * wq.x; a[0][1] += z0 * wq.y;
            a[0][2] += z0 * wq.z; a[0][3] += z0 * wq.w;
            a[1][0] += z1 * wq.x; a[1][1] += z1 * wq.y;
            a[1][2] += z1 * wq.z; a[1][3] += z1 * wq.w;
            a[2][0] += z2 * wq.x; a[2][1] += z2 * wq.y;
            a[2][2] += z2 * wq.z; a[2][3] += z2 * wq.w;
            a[3][0] += z3 * wq.x; a[3][1] += z3 * wq.y;
            a[3][2] += z3 * wq.z; a[3][3] += z3 * wq.w;
        }
        #pragma unroll
        for (int ri = 0; ri < 4; ++ri) {
            half4v o;
            o.x = (half_t)fmaxf(a[ri][0], 0.0f); o.y = (half_t)fmaxf(a[ri][1], 0.0f);
            o.z = (half_t)fmaxf(a[ri][2], 0.0f); o.w = (half_t)fmaxf(a[ri][3], 0.0f);
            *reinterpret_cast<half4v*>(&ts[(rb + ri) * 132 + cb]) = o;
        }
    }
    __syncthreads();
    for (int idx = t; idx < 128 * 64; idx += 256) Ws[idx] = W4[idx];
    __syncthreads();

    // ---- layer 2: h2 = t @ W4 + b4 (row-major ts reads) ----
    {
        int cg = t & 15, rg = t >> 4;
        int cb = cg * 4, rb = rg * 2;
        float4 b4v = *reinterpret_cast<const float4*>(&b4[cb]);
        float a[2][4];
        #pragma unroll
        for (int ri = 0; ri < 2; ++ri) {
            a[ri][0] = b4v.x; a[ri][1] = b4v.y; a[ri][2] = b4v.z; a[ri][3] = b4v.w;
        }
        #pragma unroll 4
        for (int k = 0; k < 128; ++k) {
            float t0 = (float)ts[rb * 132 + k];
            float t1 = (float)ts[(rb + 1) * 132 + k];
            float4 wq = *reinterpret_cast<const float4*>(&Ws[k * 64 + cb]);
            a[0][0] += t0 * wq.x; a[0][1] += t0 * wq.y;
            a[0][2] += t0 * wq.z; a[0][3] += t0 * wq.w;
            a[1][0] += t1 * wq.x; a[1][1] += t1 * wq.y;
            a[1][2] += t1 * wq.z; a[1][3] += t1 * wq.w;
        }
        #pragma unroll
        for (int ri = 0; ri < 2; ++ri) {
            int r = rb + ri;
            if (r < rows) {
                float4 o = {a[ri][0], a[ri][1], a[ri][2], a[ri][3]};
                *reinterpret_cast<float4*>(&h2[(size_t)(r0 + r) * 64 + cb]) = o;
            }
        }
    }
}

// ---------------- propagation ----------------
// Wave = 2 contiguous nodes interleaved, lane = channel, 1 edge per gather
// instr. z fp16 between steps (128 B rows); edata 4 B packed; compute fp32.

template <typename TI, bool WITHV>
__device__ inline void drain_node(const TI* __restrict__ zin,
                                  const int* __restrict__ edata,
                                  int& e, int end, int lane,
                                  float& a0, float& a1, float& a2, float& a3,
                                  const float* __restrict__ vin, float& vacc,
                                  int firstOnes) {
    for (; e + 8 <= end; e += 8) {
        unsigned int p0 = edata[e],     p1 = edata[e + 1], p2 = edata[e + 2], p3 = edata[e + 3];
        unsigned int p4 = edata[e + 4], p5 = edata[e + 5], p6 = edata[e + 6], p7 = edata[e + 7];
        int s0 = p0 >> 15, s1 = p1 >> 15, s2 = p2 >> 15, s3 = p3 >> 15;
        int s4 = p4 >> 15, s5 = p5 >> 15, s6 = p6 >> 15, s7 = p7 >> 15;
        float n0 = h15_2f(p0), n1 = h15_2f(p1), n2 = h15_2f(p2), n3 = h15_2f(p3);
        float n4 = h15_2f(p4), n5 = h15_2f(p5), n6 = h15_2f(p6), n7 = h15_2f(p7);
        float v0 = (float)zin[(size_t)s0 * 64 + lane];
        float v1 = (float)zin[(size_t)s1 * 64 + lane];
        float v2 = (float)zin[(size_t)s2 * 64 + lane];
        float v3 = (float)zin[(size_t)s3 * 64 + lane];
        float v4 = (float)zin[(size_t)s4 * 64 + lane];
        float v5 = (float)zin[(size_t)s5 * 64 + lane];
        float v6 = (float)zin[(size_t)s6 * 64 + lane];
        float v7 = (float)zin[(size_t)s7 * 64 + lane];
        if (WITHV) {
            if (firstOnes) vacc += (n0 + n1 + n2 + n3) + (n4 + n5 + n6 + n7);
            else vacc += n0 * vin[s0] + n1 * vin[s1] + n2 * vin[s2] + n3 * vin[s3]
                       + n4 * vin[s4] + n5 * vin[s5] + n6 * vin[s6] + n7 * vin[s7];
        }
        a0 += n0 * v0; a1 += n1 * v1; a2 += n2 * v2; a3 += n3 * v3;
        a0 += n4 * v4; a1 += n5 * v5; a2 += n6 * v6; a3 += n7 * v7;
    }
    for (; e + 2 <= end; e += 2) {
        unsigned int p0 = edata[e], p1 = edata[e + 1];
        int s0 = p0 >> 15, s1 = p1 >> 15;
        float n0 = h15_2f(p0), n1 = h15_2f(p1);
        float v0 = (float)zin[(size_t)s0 * 64 + lane];
        float v1 = (float)zin[(size_t)s1 * 64 + lane];
        if (WITHV) {
            vacc += firstOnes ? (n0 + n1) : (n0 * vin[s0] + n1 * vin[s1]);
        }
        a0 += n0 * v0; a1 += n1 * v1;
    }
    if (e < end) {
        unsigned int p0 = edata[e];
        int s0 = p0 >> 15;
        float n0 = h15_2f(p0);
        a0 += n0 * (float)zin[(size_t)s0 * 64 + lane];
        if (WITHV) vacc += firstOnes ? n0 : n0 * vin[s0];
        ++e;
    }
}

template <typename TI, typename TO, bool WITHV>
__global__ __launch_bounds__(256) void prop64_kernel(const TI* __restrict__ zin,
                                                     const float* __restrict__ h,
                                                     const int* __restrict__ rowptr,
                                                     const int* __restrict__ edata,
                                                     const float* __restrict__ dinv,
                                                     TO* __restrict__ zout,
                                                     const float* __restrict__ vin,
                                                     float* __restrict__ vout,
                                                     int N, int firstOnes) {
    int wave = threadIdx.x >> 6;
    int lane = threadIdx.x & 63;
    int pair = blockIdx.x * 4 + wave;
    int iA = pair * 2;
    if (iA >= N) return;
    iA = __builtin_amdgcn_readfirstlane(iA);
    int iB = iA + 1;
    bool hasB = (iB < N);
    int begA = rowptr[iA], endA = rowptr[iA + 1];
    int begB = endA, endB = hasB ? rowptr[iB + 1] : endA;
    float diA = dinv[iA];
    float diB = hasB ? dinv[iB] : 0.0f;
    size_t liA = (size_t)iA * 64 + lane;
    size_t liB = (size_t)iB * 64 + lane;
    float a0 = diA * diA * (float)zin[liA], a1 = 0.0f, a2 = 0.0f, a3 = 0.0f;
    float b0 = hasB ? diB * diB * (float)zin[liB] : 0.0f, b1 = 0.0f, b2 = 0.0f, b3 = 0.0f;
    float vaccA = 0.0f, vaccB = 0.0f;
    int eA = begA, eB = begB;

    while (eA + 8 <= endA && eB + 8 <= endB) {
        unsigned int pA0 = edata[eA],     pA1 = edata[eA + 1];
        unsigned int pA2 = edata[eA + 2], pA3 = edata[eA + 3];
        unsigned int pA4 = edata[eA + 4], pA5 = edata[eA + 5];
        unsigned int pA6 = edata[eA + 6], pA7 = edata[eA + 7];
        unsigned int pB0 = edata[eB],     pB1 = edata[eB + 1];
        unsigned int pB2 = edata[eB + 2], pB3 = edata[eB + 3];
        unsigned int pB4 = edata[eB + 4], pB5 = edata[eB + 5];
        unsigned int pB6 = edata[eB + 6], pB7 = edata[eB + 7];
        int sA0 = pA0 >> 15, sA1 = pA1 >> 15, sA2 = pA2 >> 15, sA3 = pA3 >> 15;
        int sA4 = pA4 >> 15, sA5 = pA5 >> 15, sA6 = pA6 >> 15, sA7 = pA7 >> 15;
        int sB0 = pB0 >> 15, sB1 = pB1 >> 15, sB2 = pB2 >> 15, sB3 = pB3 >> 15;
        int sB4 = pB4 >> 15, sB5 = pB5 >> 15, sB6 = pB6 >> 15, sB7 = pB7 >> 15;
        float nA0 = h15_2f(pA0), nA1 = h15_2f(pA1), nA2 = h15_2f(pA2), nA3 = h15_2f(pA3);
        float nA4 = h15_2f(pA4), nA5 = h15_2f(pA5), nA6 = h15_2f(pA6), nA7 = h15_2f(pA7);
        float nB0 = h15_2f(pB0), nB1 = h15_2f(pB1), nB2 = h15_2f(pB2), nB3 = h15_2f(pB3);
        float nB4 = h15_2f(pB4), nB5 = h15_2f(pB5), nB6 = h15_2f(pB6), nB7 = h15_2f(pB7);
        float vA0 = (float)zin[(size_t)sA0 * 64 + lane];
        float vA1 = (float)zin[(size_t)sA1 * 64 + lane];
        float vA2 = (float)zin[(size_t)sA2 * 64 + lane];
        float vA3 = (float)zin[(size_t)sA3 * 64 + lane];
        float vA4 = (float)zin[(size_t)sA4 * 64 + lane];
        float vA5 = (float)zin[(size_t)sA5 * 64 + lane];
        float vA6 = (float)zin[(size_t)sA6 * 64 + lane];
        float vA7 = (float)zin[(size_t)sA7 * 64 + lane];
        float vB0 = (float)zin[(size_t)sB0 * 64 + lane];
        float vB1 = (float)zin[(size_t)sB1 * 64 + lane];
        float vB2 = (float)zin[(size_t)sB2 * 64 + lane];
        float vB3 = (float)zin[(size_t)sB3 * 64 + lane];
        float vB4 = (float)zin[(size_t)sB4 * 64 + lane];
        float vB5 = (float)zin[(size_t)sB5 * 64 + lane];
        float vB6 = (float)zin[(size_t)sB6 * 64 + lane];
        float vB7 = (float)zin[(size_t)sB7 * 64 + lane];
        if (WITHV) {
            if (firstOnes) {
                vaccA += (nA0 + nA1 + nA2 + nA3) + (nA4 + nA5 + nA6 + nA7);
                vaccB += (nB0 + nB1 + nB2 + nB3) + (nB4 + nB5 + nB6 + nB7);
            } else {
                vaccA += nA0 * vin[sA0] + nA1 * vin[sA1] + nA2 * vin[sA2]
                       + nA3 * vin[sA3] + nA4 * vin[sA4] + nA5 * vin[sA5]
                       + nA6 * vin[sA6] + nA7 * vin[sA7];
                vaccB += nB0 * vin[sB0] + nB1 * vin[sB1] + nB2 * vin[sB2]
                       + nB3 * vin[sB3] + nB4 * vin[sB4] + nB5 * vin[sB5]
                       + nB6 * vin[sB6] + nB7 * vin[sB7];
            }
        }
        a0 += nA0 * vA0; a1 += nA1 * vA1; a2 += nA2 * vA2; a3 += nA3 * vA3;
        a0 += nA4 * vA4; a1 += nA5 * vA5; a2 += nA6 * vA6; a3 += nA7 * vA7;
        b0 += nB0 * vB0; b1 += nB1 * vB1; b2 += nB2 * vB2; b3 += nB3 * vB3;
        b0 += nB4 * vB4; b1 += nB5 * vB5; b2 += nB6 * vB6; b3 += nB7 * vB7;
        eA += 8; eB += 8;
    }
    drain_node<TI, WITHV>(zin, edata, eA, endA, lane, a0, a1, a2, a3, vin, vaccA, firstOnes);
    if (hasB)
        drain_node<TI, WITHV>(zin, edata, eB, endB, lane, b0, b1, b2, b3, vin, vaccB, firstOnes);

    float accA = (a0 + a1) + (a2 + a3);
    zout[liA] = (TO)((1.0f - PROP_ALPHA) * accA + PROP_ALPHA * h[liA]);
    if (hasB) {
        float accB = (b0 + b1) + (b2 + b3);
        zout[liB] = (TO)((1.0f - PROP_ALPHA) * accB + PROP_ALPHA * h[liB]);
    }
    if (WITHV) {
        if (lane == 0) {
            float selfA = firstOnes ? 1.0f : vin[iA];
            vout[iA] = (1.0f - PROP_ALPHA) * (vaccA + diA * diA * selfA) + PROP_ALPHA;
            if (hasB) {
                float selfB = firstOnes ? 1.0f : vin[iB];
                vout[iB] = (1.0f - PROP_ALPHA) * (vaccB + diB * diB * selfB) + PROP_ALPHA;
            }
        }
    }
}

// ---------------- launch ----------------

extern "C" void kernel_launch(void* const* d_in, const int* in_sizes, int n_in,
                              void* d_out, int out_size, void* d_ws, size_t ws_size,
                              hipStream_t stream) {
    const float* x  = (const float*)d_in[0];
    const int*   ei = (const int*)d_in[1];
    const float* W3 = (const float*)d_in[2];
    const float* b3 = (const float*)d_in[3];
    const float* W4 = (const float*)d_in[4];
    const float* b4 = (const float*)d_in[5];
    float* out = (float*)d_out;

    int N = in_sizes[0] / 64;   // IN_CH = 64
    int E = in_sizes[1] / 2;
    const int* srcA = ei;
    const int* dstA = ei + E;

    char* ws = (char*)d_ws;
    size_t off = 0;
    auto alloc = [&](size_t bytes) -> void* {
        void* p = ws + off;
        off = (off + bytes + 255) & ~(size_t)255;
        return p;
    };

    int nScanB = (N + 255) / 256;

    int*    degI   = (int*)alloc((size_t)N * 4);
    int*    rowptr = (int*)alloc(((size_t)N + 1) * 4);
    int*    rowctr = (int*)alloc((size_t)N * 4);
    int*    bsums  = (int*)alloc((size_t)nScanB * 4);
    float*  dinv   = (float*)alloc((size_t)N * 4);
    int*    edata  = (int*)alloc((size_t)E * 4);
    float*  vA     = (float*)alloc((size_t)N * 4);
    float*  vB     = (float*)alloc((size_t)N * 4);
    half_t* z16A   = (half_t*)alloc((size_t)N * 64 * 2);
    half_t* z16B   = (half_t*)alloc((size_t)N * 64 * 2);
    float*  hbuf   = (float*)alloc((size_t)N * 64 * 4);

    hipMemsetAsync(degI, 0, (size_t)N * 4, stream);
    hipMemsetAsync(rowctr, 0, (size_t)N * 4, stream);

    // --- CSR build ---
    hist_kernel<<<(E + 255) / 256, 256, 0, stream>>>(dstA, degI, E);
    dinv_kernel<<<(N + 255) / 256, 256, 0, stream>>>(degI, dinv, N);
    scan1_kernel<<<nScanB, 256, 0, stream>>>(degI, rowptr, bsums, N);
    scan2_kernel<<<1, 256, 0, stream>>>(bsums, nScanB);
    scan3_kernel<<<nScanB, 256, 0, stream>>>(rowptr, bsums, N);
    scatter_kernel<<<(E + 255) / 256, 256, 0, stream>>>(srcA, dstA, rowptr, rowctr,
                                                        dinv, edata, E);

    int nPairs = (N + 1) / 2;
    int propBlocks = (nPairs + 3) / 4;

    // --- prop1: zx = M*x, z fp16 between steps, fused v = M*ones ---
    // s0: fp32 x -> z16A; odd s: z16A -> z16B; even s: z16B -> z16A; s9 -> z16B
    for (int s = 0; s < PROP_KSTEPS; ++s) {
        const float* vi = (s & 1) ? vA : vB;   // s0: unused (firstOnes)
        float*       vo = (s & 1) ? vB : vA;
        if (s == 0) vi = vB;
        if (s == 0) {
            prop64_kernel<float, half_t, true><<<propBlocks, 256, 0, stream>>>(
                x, x, rowptr, edata, dinv, z16A, vi, vo, N, 1);
        } else {
            const half_t* in = (s & 1) ? z16A : z16B;
            half_t*       o  = (s & 1) ? z16B : z16A;
            prop64_kernel<half_t, half_t, true><<<propBlocks, 256, 0, stream>>>(
                in, x, rowptr, edata, dinv, o, vi, vo, N, 0);
        }
    }
    // zx (fp16) in z16B, v in vB

    // --- h2 = relu(zx@W3 + v*b3^T)@W4 + b4 ---
    fusedmlp_kernel<<<(N + 31) / 32, 256, 0, stream>>>(z16B, vB, W3, b3, W4, b4, hbuf, N);

    // --- prop2: out = M*h2 ---
    for (int s = 0; s < PROP_KSTEPS; ++s) {
        if (s == 0) {
            prop64_kernel<float, half_t, false><<<propBlocks, 256, 0, stream>>>(
                hbuf, hbuf, rowptr, edata, dinv, z16A, nullptr, nullptr, N, 0);
        } else if (s == PROP_KSTEPS - 1) {
            prop64_kernel<half_t, float, false><<<propBlocks, 256, 0, stream>>>(
                z16A, hbuf, rowptr, edata, dinv, out, nullptr, nullptr, N, 0);
        } else {
            const half_t* in = (s & 1) ? z16A : z16B;
            half_t*       o  = (s & 1) ? z16B : z16A;
            prop64_kernel<half_t, half_t, false><<<propBlocks, 256, 0, stream>>>(
                in, hbuf, rowptr, edata, dinv, o, nullptr, nullptr, N, 0);
        }
    }
}